// Round 10
// baseline (263.618 us; speedup 1.0000x reference)
//
#include <hip/hip_runtime.h>
#include <stdint.h>

#define B_ 8
#define N_ 8192
#define S_ 2048
#define C1_ 128
#define C2_ 256
#define IN_ 384
#define H1_ 256
#define H2_ 128
#define M_ (B_*N_)   // 65536 rows

typedef short bf16x8 __attribute__((ext_vector_type(8)));
typedef float f32x4 __attribute__((ext_vector_type(4)));
typedef short short4v __attribute__((ext_vector_type(4)));
typedef unsigned short ushort4v __attribute__((ext_vector_type(4)));

__device__ __forceinline__ float bf2f(unsigned short s){
  union { unsigned int u; float f; } x; x.u = ((unsigned int)s) << 16; return x.f;
}
__device__ __forceinline__ unsigned short f2bf(float f){
  union { float f; unsigned int u; } x; x.f = f;
  unsigned int u = x.u;
  unsigned int r = (u + 0x7FFFu + ((u >> 16) & 1u)) >> 16;
  return (unsigned short)r;
}

// fragment-major layout: element (m,k) of a row-major [M][K] matrix lives at
// tile (m/16, k/32) * 512 + lane-order offset; a wave's fragment = 1 KB contiguous burst.
__device__ __forceinline__ size_t fragaddr(int m, int k, int K){
  return ((size_t)((m >> 4) * (K >> 5) + (k >> 5)) << 9)
       + (size_t)((((k >> 3) & 3) << 7) + ((m & 15) << 3) + (k & 7));
}

// async global->LDS, 16B per lane (m97 mechanism: dest wave-uniform base + lane*16)
__device__ __forceinline__ void gload_lds16(const unsigned short* g, unsigned short* l){
  __builtin_amdgcn_global_load_lds(
      (const __attribute__((address_space(1))) unsigned int*)g,
      (__attribute__((address_space(3))) unsigned int*)l, 16, 0, 0);
}

#define PIECES_ 8
#define SPP_ (S_ / PIECES_)   // 256 -> local idx fits 8 bits

__device__ __forceinline__ void insert_k(float& k0, float& k1, float& k2, float x){
  k2 = __builtin_amdgcn_fmed3f(k1, k2, x);
  k1 = __builtin_amdgcn_fmed3f(k0, k1, x);
  k0 = fminf(k0, x);
}

__device__ __forceinline__ void insert3(float& d0, float& d1, float& d2,
                                        int& i0, int& i1, int& i2,
                                        float x, int s){
  bool b0 = x < d0, b1 = x < d1, b2 = x < d2;
  i2 = b1 ? i1 : (b2 ? s : i2);
  i1 = b0 ? i0 : (b1 ? s : i1);
  i0 = b0 ? s : i0;
  d2 = __builtin_amdgcn_fmed3f(d1, d2, x);
  d1 = __builtin_amdgcn_fmed3f(d0, d1, x);
  d0 = fminf(d0, x);
}

// ---------------- kernel A: knn (piece-split, VALU) || p2t transpose (memory) || weights
// grid 6528: [0,4096) period 2 {knn, p2t} (1:1 -- knn gets 1/2 CU share during the p2t
// drain phase instead of R9's 1/3; p2t is BW-bound and saturates HBM even at low share);
// [4096,6144) p2t tail; [6144,6528) weights. knn floor ~40us (R0/R3/R4-characterized);
// A = p2t-phase interference + knn wall.
__global__ __launch_bounds__(256) void p2t_knn_kernel(
    const float* W1, const float* W2, const float* p2,
    const float* xyz1, const float* xyz2,
    unsigned short* w1b, unsigned short* w2b,
    unsigned short* p2t, float* partd, int* parti)
{
  __shared__ __align__(16) char smraw[4352];               // union: tile 4224B | pts 4096B
  float (*tile)[33] = reinterpret_cast<float(*)[33]>(smraw);
  float4* pts = reinterpret_cast<float4*>(smraw);
  const int bx = blockIdx.x, t = threadIdx.x;

  if (bx >= 6144){
    int i = (bx - 6144) * 256 + t;
    if (i < 256*384){
      int row = i / 384, col = i - row*384;
      w1b[fragaddr(row, col, 384)] = f2bf(W1[i]);
    }
    if (i < 128*256){
      int row = i >> 8, col = i & 255;
      w2b[fragaddr(row, col, 256)] = f2bf(W2[i]);
    }
    return;
  }

  int knnId = -1, p2tId;
  if (bx < 4096){
    if ((bx & 1) == 0) knnId = bx >> 1;
    else               p2tId = bx >> 1;
  } else {
    p2tId = 2048 + (bx - 4096);
  }

  if (knnId >= 0){
    // ---- knn role: kid in [0,2048), one piece per block (R5-verbatim + cb[8] batch) ----
    int kid = knnId;
    int nb = kid & 31, b = (kid >> 5) & 7, piece = kid >> 8;
    int n = nb * 256 + t;
    int base = piece * SPP_;
    const float* x2 = xyz2 + (size_t)b * 3 * S_;
    {
      float px = x2[base + t], py = x2[S_ + base + t], pz = x2[2*S_ + base + t];
      pts[t] = make_float4(-2.f*px, -2.f*py, -2.f*pz, px*px + py*py + pz*pz);
    }
    __syncthreads();
    const float* x1 = xyz1 + (size_t)b * 3 * N_;
    float ax = x1[n], ay = x1[N_ + n], az = x1[2*N_ + n];
    float x1sq = ax*ax + ay*ay + az*az;

    const float KINIT = __uint_as_float(0x7F000000u);
    float ka[3] = {KINIT, KINIT, KINIT};
    float kb[3] = {KINIT, KINIT, KINIT};

    for (int s = 0; s < SPP_; s += 8){
      float4 cb[8];
      #pragma unroll
      for (int u = 0; u < 8; u++) cb[u] = pts[s + u];
      #pragma unroll
      for (int u = 0; u < 8; u++){
        float dd = fmaf(ax, cb[u].x, fmaf(ay, cb[u].y, fmaf(az, cb[u].z, cb[u].w + x1sq)));
        float key = __uint_as_float((__float_as_uint(dd) & 0xFFFFFF00u) | (unsigned)(s + u));
        if (u & 1) insert_k(kb[0], kb[1], kb[2], key);
        else       insert_k(ka[0], ka[1], ka[2], key);
      }
    }
    insert_k(ka[0], ka[1], ka[2], kb[0]);
    insert_k(ka[0], ka[1], ka[2], kb[1]);
    insert_k(ka[0], ka[1], ka[2], kb[2]);

    float ed[3]; int ei[3];
    #pragma unroll
    for (int j = 0; j < 3; j++){
      int li = (int)(__float_as_uint(ka[j]) & 0xFFu);
      float4 c = pts[li];
      float dd = fmaf(ax, c.x, fmaf(ay, c.y, fmaf(az, c.z, c.w + x1sq)));
      ed[j] = fmaxf(dd, 0.f);
      ei[j] = base + li;
    }

    size_t g = (size_t)b * N_ + n;
    partd[(piece*3 + 0)*(size_t)M_ + g] = ed[0];
    partd[(piece*3 + 1)*(size_t)M_ + g] = ed[1];
    partd[(piece*3 + 2)*(size_t)M_ + g] = ed[2];
    parti[(piece*3 + 0)*(size_t)M_ + g] = ei[0];
    parti[(piece*3 + 1)*(size_t)M_ + g] = ei[1];
    parti[(piece*3 + 2)*(size_t)M_ + g] = ei[2];
    return;
  }

  // ---- p2t transpose role: pid in [0,4096) ----
  {
    int pid = p2tId;
    int b = pid >> 9, rem = pid & 511;
    int l0 = (rem & 63) * 32, r0 = (rem >> 6) * 32;   // l: point in S, r: channel in C2
    int tx = t & 31, ty = t >> 5;
    const float* src = p2 + (size_t)b * C2_ * S_;
    #pragma unroll
    for (int rr = ty; rr < 32; rr += 8)
      tile[rr][tx] = src[(size_t)(r0 + rr) * S_ + l0 + tx];
    __syncthreads();
    unsigned short* dst = p2t + (size_t)b * S_ * C2_;
    #pragma unroll
    for (int rr = ty; rr < 32; rr += 8)
      dst[(size_t)(l0 + rr) * C2_ + r0 + tx] = f2bf(tile[tx][rr]);
  }
}

// ---------------- merge: coalesced thread-per-query reduction of piece-partials ---------
// (R9-verified: removed the 61us latency chain.) 25.2 MB read + 1.75 MB write, BW-bound.
__global__ __launch_bounds__(256) void merge_kernel(const float* __restrict__ partd,
                                                    const int* __restrict__ parti,
                                                    int* __restrict__ ibuf,
                                                    float* __restrict__ wbuf){
  size_t g = (size_t)blockIdx.x * 256 + threadIdx.x;
  float d0 = partd[0*(size_t)M_ + g], d1 = partd[1*(size_t)M_ + g], d2 = partd[2*(size_t)M_ + g];
  int   i0 = parti[0*(size_t)M_ + g], i1 = parti[1*(size_t)M_ + g], i2 = parti[2*(size_t)M_ + g];
  #pragma unroll
  for (int p = 1; p < PIECES_; p++)
    #pragma unroll
    for (int j = 0; j < 3; j++)
      insert3(d0, d1, d2, i0, i1, i2,
              partd[(p*3 + j)*(size_t)M_ + g], parti[(p*3 + j)*(size_t)M_ + g]);
  float r0 = 1.f/(d0 + 1e-8f), r1 = 1.f/(d1 + 1e-8f), r2 = 1.f/(d2 + 1e-8f);
  float rs = 1.f/(r0 + r1 + r2);
  ibuf[0*(size_t)M_ + g] = i0;    ibuf[1*(size_t)M_ + g] = i1;    ibuf[2*(size_t)M_ + g] = i2;
  wbuf[0*(size_t)M_ + g] = r0*rs; wbuf[1*(size_t)M_ + g] = r1*rs; wbuf[2*(size_t)M_ + g] = r2*rs;
}

// ---------------- kernel C: gather/interp (vectorized) || p1->x streaming (memory) ------
// grid 12288: period 3 {1 gather, 2 p1}. Gather rewritten 4-channels-per-lane (G13):
// R8's counters showed 1.7 TB/s at 70% occupancy = request-rate-bound on 2B/lane accesses.
// Now: one wave per query; lane ln covers channels 4ln..4ln+3 -> each p2t row read is one
// ushort4 (512B/wave-request, 4x fewer 4x bigger), frag store is one 8B short4.
__global__ __launch_bounds__(256) void xbuild_kernel(
    const float* p1, const unsigned short* p2t,
    const int* ibuf, const float* wbuf, unsigned short* x)
{
  __shared__ __align__(16) char smraw[4352];
  float (*tile)[33] = reinterpret_cast<float(*)[33]>(smraw);
  int*   sidx = reinterpret_cast<int*>(smraw);          // [16][3]
  float* swgt = reinterpret_cast<float*>(smraw + 192);  // [16][3]
  const int bx = blockIdx.x, t = threadIdx.x;
  const int per = bx / 3, r = bx % 3;

  if (r == 0){
    int base = per * 16;
    if (t < 64){
      int q = t >> 2, j = t & 3;
      if (j < 3){
        sidx[q*3 + j] = ibuf[(size_t)j*M_ + base + q];
        swgt[q*3 + j] = wbuf[(size_t)j*M_ + base + q];
      }
    }
    __syncthreads();
    const int wv = t >> 6, ln = t & 63;
    #pragma unroll
    for (int kq = 0; kq < 4; kq++){
      int k = kq*4 + wv;                  // query slot 0..15, one per wave per step
      int g = base + k;
      int b = g >> 13;
      const unsigned short* p = p2t + (size_t)b * S_ * C2_;
      float a0 = 0.f, a1 = 0.f, a2 = 0.f, a3 = 0.f;
      #pragma unroll
      for (int j = 0; j < 3; j++){
        ushort4v v = *(const ushort4v*)(p + (size_t)sidx[k*3+j]*C2_ + 4*ln);
        float w = swgt[k*3+j];
        a0 = fmaf(w, bf2f(v[0]), a0);
        a1 = fmaf(w, bf2f(v[1]), a1);
        a2 = fmaf(w, bf2f(v[2]), a2);
        a3 = fmaf(w, bf2f(v[3]), a3);
      }
      short4v o;
      o[0] = (short)f2bf(a0); o[1] = (short)f2bf(a1);
      o[2] = (short)f2bf(a2); o[3] = (short)f2bf(a3);
      // frag addr for channels c=4ln..4ln+3 of row g (j contiguous -> aligned 8B store)
      size_t a = ((size_t)((g >> 4)*12 + 4 + (ln >> 3)) << 9)
               + (size_t)((((ln >> 1) & 3) << 7) + ((g & 15) << 3) + ((ln & 1) * 4));
      *(short4v*)(x + a) = o;
    }
    return;
  }

  // ---- p1 -> x frag cols 0..127: pid in [0,8192) ----
  {
    int pid = per*2 + (r - 1);
    int b = pid >> 10, rem = pid & 1023;
    int l0 = (rem & 255) * 32, r0 = (rem >> 8) * 32;  // l: point in N, r: channel in C1
    int tx = t & 31, ty = t >> 5;
    const float* src = p1 + (size_t)b * C1_ * N_;
    #pragma unroll
    for (int rr = ty; rr < 32; rr += 8)
      tile[rr][tx] = src[(size_t)(r0 + rr) * N_ + l0 + tx];
    __syncthreads();
    #pragma unroll
    for (int rr = ty; rr < 32; rr += 8){
      int g = b * N_ + l0 + rr;
      size_t a = ((size_t)((g >> 4)*12 + (r0 >> 5)) << 9)
               + (size_t)((((tx >> 3) & 3) << 7) + ((g & 15) << 3) + (tx & 7));
      x[a] = f2bf(tile[tx][rr]);
    }
  }
}

// ---------------- BN-affine + relu on one bf16x8 A-fragment ----------------
__device__ __forceinline__ bf16x8 bn_relu_frag(bf16x8 v, const float* a, const float* c, int kb){
  union { bf16x8 h; unsigned short s[8]; } u; u.h = v;
  union { float4 v4; float f[4]; } a0, a1, c0, c1;
  a0.v4 = *(const float4*)(a + kb);  a1.v4 = *(const float4*)(a + kb + 4);
  c0.v4 = *(const float4*)(c + kb);  c1.v4 = *(const float4*)(c + kb + 4);
  #pragma unroll
  for (int j = 0; j < 4; j++){
    float f0 = fmaf(a0.f[j], bf2f(u.s[j]),     c0.f[j]);
    float f1 = fmaf(a1.f[j], bf2f(u.s[j + 4]), c1.f[j]);
    u.s[j]     = f2bf(fmaxf(f0, 0.f));
    u.s[j + 4] = f2bf(fmaxf(f1, 0.f));
  }
  return u.h;
}

// ---------------- m97-style MFMA GEMM, BK=64, single-buffer (R1 structure) --------------
// Stats epilogue: NO global atomics (R3: ~2x on both GEMMs).
template<int K, bool HAS_AFF, bool OUT_FRAG>
__global__ __launch_bounds__(256) void gemm_lds_kernel(
    const unsigned short* __restrict__ A, const unsigned short* __restrict__ Wf,
    unsigned short* __restrict__ Cout, int Ntot,
    float* pbuf, const float* aff_a, const float* aff_c)
{
  constexpr int KT = K / 32;
  __shared__ unsigned short smA[128*64];   // 16 KB: [m-chunk 0..7][k-chunk 0..1][512]
  __shared__ unsigned short smB[128*64];   // 16 KB
  __shared__ float ldsStat[256];

  const int t = threadIdx.x;
  const int lane = t & 63, wave = t >> 6;
  const int ln = lane & 15, lq = lane >> 4;
  const int wm = wave >> 1, wn = wave & 1;
  const int mtb = blockIdx.x * 8;
  const int ntb = blockIdx.y * 8;
  const int mtw = mtb + wm * 4;
  const int n0  = blockIdx.y * 128 + wn * 64;

  ldsStat[t] = 0.f;

  const int c0 = 2*wave, c1 = 2*wave + 1;   // this wave's staging chunks

  const f32x4 fzero = {0.f, 0.f, 0.f, 0.f};
  f32x4 acc[4][4];
  #pragma unroll
  for (int i = 0; i < 4; i++)
    #pragma unroll
    for (int j = 0; j < 4; j++) acc[i][j] = fzero;

  for (int kk = 0; kk < KT; kk += 2){
    #pragma unroll
    for (int q = 0; q < 2; q++){
      gload_lds16(A  + (((size_t)((mtb + c0)*KT + kk + q)) << 9) + lane*8,
                  &smA[((c0*2 + q) << 9) + lane*8]);
      gload_lds16(A  + (((size_t)((mtb + c1)*KT + kk + q)) << 9) + lane*8,
                  &smA[((c1*2 + q) << 9) + lane*8]);
      gload_lds16(Wf + (((size_t)((ntb + c0)*KT + kk + q)) << 9) + lane*8,
                  &smB[((c0*2 + q) << 9) + lane*8]);
      gload_lds16(Wf + (((size_t)((ntb + c1)*KT + kk + q)) << 9) + lane*8,
                  &smB[((c1*2 + q) << 9) + lane*8]);
    }
    __syncthreads();
    #pragma unroll
    for (int q = 0; q < 2; q++){
      bf16x8 af[4], bfr[4];
      #pragma unroll
      for (int i = 0; i < 4; i++)
        af[i] = *(const bf16x8*)(&smA[(((wm*4 + i)*2 + q) << 9) + lane*8]);
      #pragma unroll
      for (int j = 0; j < 4; j++)
        bfr[j] = *(const bf16x8*)(&smB[(((wn*4 + j)*2 + q) << 9) + lane*8]);
      if (HAS_AFF){
        const int kb = (kk + q)*32 + lq*8;
        #pragma unroll
        for (int i = 0; i < 4; i++) af[i] = bn_relu_frag(af[i], aff_a, aff_c, kb);
      }
      #pragma unroll
      for (int i = 0; i < 4; i++)
        #pragma unroll
        for (int j = 0; j < 4; j++)
          acc[i][j] = __builtin_amdgcn_mfma_f32_16x16x32_bf16(af[i], bfr[j], acc[i][j], 0, 0, 0);
    }
    __syncthreads();
  }

  #pragma unroll
  for (int j = 0; j < 4; j++){
    int ncol = n0 + j*16 + ln;
    float s = 0.f, q = 0.f;
    #pragma unroll
    for (int i = 0; i < 4; i++){
      #pragma unroll
      for (int r = 0; r < 4; r++){
        float v = acc[i][j][r];
        if (OUT_FRAG){
          size_t a = ((size_t)((mtw + i)*8 + (ncol >> 5)) << 9)
                   + (size_t)((((ncol >> 3) & 3) << 7) + ((lq*4 + r) << 3) + (ncol & 7));
          Cout[a] = f2bf(v);
        } else {
          Cout[((size_t)((mtw + i)*16 + lq*4 + r)) * Ntot + ncol] = f2bf(v);
        }
        s += v; q += v*v;
      }
    }
    s += __shfl_xor(s, 16); s += __shfl_xor(s, 32);
    q += __shfl_xor(q, 16); q += __shfl_xor(q, 32);
    if (lq == 0){
      int colLocal = wn*64 + j*16 + ln;
      atomicAdd(&ldsStat[colLocal], s);          // LDS-scope only
      atomicAdd(&ldsStat[128 + colLocal], q);
    }
  }
  __syncthreads();
  // one coalesced 1KB burst per block; no device atomics anywhere
  pbuf[((size_t)(blockIdx.y * gridDim.x + blockIdx.x) << 8) + t] = ldsStat[t];
}

// ---------------- finalize BN: reduce per-block partials, a = g*rsqrt(var+eps) ----------
// pbuf layout: [grp(=by)][512 blocks][128 sum | 128 sq]; grid = C blocks, 256 threads.
__global__ __launch_bounds__(256) void finalize_kernel(const float* pbuf, const float* g,
                                                       const float* be, float* a_out,
                                                       float* c_out){
  __shared__ float red[8];
  int c = blockIdx.x, t = threadIdx.x;
  int grp = c >> 7, lc = c & 127;
  const float* base = pbuf + ((size_t)(grp * 512) << 8);
  float s = base[((size_t)t << 8) + lc]       + base[((size_t)(t + 256) << 8) + lc];
  float q = base[((size_t)t << 8) + 128 + lc] + base[((size_t)(t + 256) << 8) + 128 + lc];
  #pragma unroll
  for (int o = 1; o < 64; o <<= 1){ s += __shfl_xor(s, o); q += __shfl_xor(q, o); }
  int w = t >> 6;
  if ((t & 63) == 0){ red[w] = s; red[4 + w] = q; }
  __syncthreads();
  if (t == 0){
    s = red[0] + red[1] + red[2] + red[3];
    q = red[4] + red[5] + red[6] + red[7];
    float mean = s * (1.f / M_);
    float var  = q * (1.f / M_) - mean*mean;
    float a = g[c] * rsqrtf(var + 1e-5f);
    a_out[c] = a;
    c_out[c] = fmaf(-mean, a, be[c]);
  }
}

// ---------------- final: BN2-affine + relu + transpose to [B,128,N] fp32 ----------------
__global__ __launch_bounds__(256) void out_kernel(const unsigned short* y2, const float* a2,
                                                  const float* c2, float* out){
  __shared__ float lds[64][65];
  int t  = threadIdx.x;
  int b  = blockIdx.z;
  int n0 = blockIdx.y * 64;
  int c0 = blockIdx.x * 64;
  int cc = t & 63, tr = t >> 6;
  float a = a2[c0 + cc], cadd = c2[c0 + cc];
  #pragma unroll
  for (int ph = 0; ph < 16; ph++){
    int nr = tr + ph*4;
    unsigned short v = y2[((size_t)(b*N_ + n0 + nr)) * H2_ + c0 + cc];
    lds[nr][cc] = fmaxf(fmaf(a, bf2f(v), cadd), 0.f);
  }
  __syncthreads();
  #pragma unroll
  for (int ph = 0; ph < 16; ph++){
    int cr = tr + ph*4;
    out[((size_t)(b*H2_ + c0 + cr)) * N_ + n0 + cc] = lds[cc][cr];
  }
}

extern "C" void kernel_launch(void* const* d_in, const int* in_sizes, int n_in,
                              void* d_out, int out_size, void* d_ws, size_t ws_size,
                              hipStream_t stream){
  const float* xyz1 = (const float*)d_in[0];
  const float* xyz2 = (const float*)d_in[1];
  const float* p1   = (const float*)d_in[2];
  const float* p2   = (const float*)d_in[3];
  const float* W1   = (const float*)d_in[4];
  const float* g1   = (const float*)d_in[6];
  const float* be1  = (const float*)d_in[7];
  const float* W2   = (const float*)d_in[8];
  const float* g2   = (const float*)d_in[10];
  const float* be2  = (const float*)d_in[11];
  float* out = (float*)d_out;

  char* ws = (char*)d_ws;
  unsigned short* x    = (unsigned short*)(ws + 0);          // [65536][384] bf16 frag  50.3 MB
  unsigned short* p2t  = (unsigned short*)(ws + 50331648);   // [8][2048][256] bf16 row  8.4 MB
  unsigned short* y1   = (unsigned short*)(ws + 58720256);   // [65536][256] bf16 frag  33.6 MB
  unsigned short* y2   = (unsigned short*)(ws + 92274688);   // [65536][128] bf16 row   16.8 MB
  unsigned short* w1b  = (unsigned short*)(ws + 109051904);  // [256][384] bf16 frag
  unsigned short* w2b  = (unsigned short*)(ws + 109248512);  // [128][256] bf16 frag
  float*          stats= (float*)(ws + 110886912);           // a1/c1/a2/c2
  float* a1   = stats + 768;  float* c1  = stats + 1024;
  float* a2   = stats + 1280; float* c2  = stats + 1408;
  // knn partials in y1 region: partd [0,6.3MB), parti [12.6,18.9MB)
  float* partd = (float*)y1;
  int*   parti = (int*)(y1 + 6291456);
  // compact merged {idx,w} at y1+20MB / y1+22MB (dead before gemm1 overwrites y1)
  int*   ibuf = (int*)  (ws + 58720256 + 20971520);          // 768 KB
  float* wbuf = (float*)(ws + 58720256 + 23068672);          // 768 KB
  // gemm stats partials: gemm1 -> p2t region (dead after xbuild), gemm2 -> x region
  float* pbuf1 = (float*)p2t;
  float* pbuf2 = (float*)x;

  // A: knn (2048, 1:1 front-loaded) || p2t (4096) || weights (384)
  p2t_knn_kernel<<<6528, 256, 0, stream>>>(W1, W2, p2, xyz1, xyz2, w1b, w2b, p2t, partd, parti);
  // merge: coalesced thread-per-query partials reduction -> {idx3,w3}
  merge_kernel<<<256, 256, 0, stream>>>(partd, parti, ibuf, wbuf);
  // C: gather (4096, vectorized 4ch/lane) || p1->x streaming (8192)
  xbuild_kernel<<<12288, 256, 0, stream>>>(p1, p2t, ibuf, wbuf, x);
  // gemm1: M=65536, N=256, K=384; block 128x128 -> grid (512, 2); y1 in frag layout (K=256)
  gemm_lds_kernel<384, false, true><<<dim3(512, 2), 256, 0, stream>>>(
      x, w1b, y1, 256, pbuf1, nullptr, nullptr);
  finalize_kernel<<<256, 256, 0, stream>>>(pbuf1, g1, be1, a1, c1);
  // gemm2: M=65536, N=128, K=256; block 128x128 -> grid (512, 1); y2 row layout
  gemm_lds_kernel<256, true, false><<<dim3(512, 1), 256, 0, stream>>>(
      y1, w2b, y2, 128, pbuf2, a1, c1);
  finalize_kernel<<<128, 256, 0, stream>>>(pbuf2, g2, be2, a2, c2);
  out_kernel<<<dim3(2, 128, 8), 256, 0, stream>>>(y2, a2, c2, out);
}

// Round 11
// 242.947 us; speedup vs baseline: 1.0851x; 1.0851x over previous
//
#include <hip/hip_runtime.h>
#include <stdint.h>

#define B_ 8
#define N_ 8192
#define S_ 2048
#define C1_ 128
#define C2_ 256
#define IN_ 384
#define H1_ 256
#define H2_ 128
#define M_ (B_*N_)   // 65536 rows

typedef short bf16x8 __attribute__((ext_vector_type(8)));
typedef float f32x4 __attribute__((ext_vector_type(4)));
typedef short short4v __attribute__((ext_vector_type(4)));
typedef unsigned short ushort4v __attribute__((ext_vector_type(4)));

__device__ __forceinline__ float bf2f(unsigned short s){
  union { unsigned int u; float f; } x; x.u = ((unsigned int)s) << 16; return x.f;
}
__device__ __forceinline__ unsigned short f2bf(float f){
  union { float f; unsigned int u; } x; x.f = f;
  unsigned int u = x.u;
  unsigned int r = (u + 0x7FFFu + ((u >> 16) & 1u)) >> 16;
  return (unsigned short)r;
}

// fragment-major layout: element (m,k) of a row-major [M][K] matrix lives at
// tile (m/16, k/32) * 512 + lane-order offset; a wave's fragment = 1 KB contiguous burst.
__device__ __forceinline__ size_t fragaddr(int m, int k, int K){
  return ((size_t)((m >> 4) * (K >> 5) + (k >> 5)) << 9)
       + (size_t)((((k >> 3) & 3) << 7) + ((m & 15) << 3) + (k & 7));
}

// async global->LDS, 16B per lane (m97 mechanism: dest wave-uniform base + lane*16)
__device__ __forceinline__ void gload_lds16(const unsigned short* g, unsigned short* l){
  __builtin_amdgcn_global_load_lds(
      (const __attribute__((address_space(1))) unsigned int*)g,
      (__attribute__((address_space(3))) unsigned int*)l, 16, 0, 0);
}

#define PIECES_ 8
#define SPP_ (S_ / PIECES_)   // 256 -> local idx fits 8 bits

__device__ __forceinline__ void insert_k(float& k0, float& k1, float& k2, float x){
  k2 = __builtin_amdgcn_fmed3f(k1, k2, x);
  k1 = __builtin_amdgcn_fmed3f(k0, k1, x);
  k0 = fminf(k0, x);
}

__device__ __forceinline__ void insert3(float& d0, float& d1, float& d2,
                                        int& i0, int& i1, int& i2,
                                        float x, int s){
  bool b0 = x < d0, b1 = x < d1, b2 = x < d2;
  i2 = b1 ? i1 : (b2 ? s : i2);
  i1 = b0 ? i0 : (b1 ? s : i1);
  i0 = b0 ? s : i0;
  d2 = __builtin_amdgcn_fmed3f(d1, d2, x);
  d1 = __builtin_amdgcn_fmed3f(d0, d1, x);
  d0 = fminf(d0, x);
}

// ---------------- fused prep + knn: interleaved block roles (R5-verbatim, 242.3 best) ---
// 128 periods of 115 blocks: r<16 -> knn (2048 blocks, piece-split, VALU-bound);
// r>=16 -> prep (12672: weights/stats [0,384), p2t [384,4480), p1->x [4480,12672)).
// R10 lesson: every A/B re-split of these roles measured WORSE (A+xbuild >= 96us vs this
// kernel's 59); the 16:99 mix is the best-measured co-schedule. Do not re-split.
__global__ __launch_bounds__(256) void prep_knn_fused(
    const float* W1, const float* W2, const float* p2, const float* p1,
    const float* xyz1, const float* xyz2,
    unsigned short* w1b, unsigned short* w2b, float* stats,
    unsigned short* p2t, unsigned short* x,
    float* partd, int* parti)
{
  __shared__ __align__(16) char smraw[4224];               // union: tile 4224B | pts 4096B
  float (*tile)[33] = reinterpret_cast<float(*)[33]>(smraw);
  float4* pts = reinterpret_cast<float4*>(smraw);

  const int per = blockIdx.x / 115;
  const int r   = blockIdx.x % 115;
  const int t   = threadIdx.x;

  if (r < 16){
    // ---- knn role ----
    int kid = per*16 + r;                      // [0,2048)
    int nb = kid & 31, b = (kid >> 5) & 7, piece = kid >> 8;
    int n = nb*256 + t;
    int base = piece * SPP_;
    const float* x2 = xyz2 + (size_t)b * 3 * S_;
    {
      float px = x2[base + t], py = x2[S_ + base + t], pz = x2[2*S_ + base + t];
      pts[t] = make_float4(-2.f*px, -2.f*py, -2.f*pz, px*px + py*py + pz*pz);
    }
    __syncthreads();
    const float* x1 = xyz1 + (size_t)b * 3 * N_;
    float ax = x1[n], ay = x1[N_ + n], az = x1[2*N_ + n];
    float x1sq = ax*ax + ay*ay + az*az;

    const float KINIT = __uint_as_float(0x7F000000u);
    float k[2][3];
    k[0][0]=k[0][1]=k[0][2]=KINIT;
    k[1][0]=k[1][1]=k[1][2]=KINIT;

    for (int s = 0; s < SPP_; s += 8){
      #pragma unroll
      for (int u = 0; u < 8; u++){
        float4 c = pts[s + u];
        float dd = fmaf(ax, c.x, fmaf(ay, c.y, fmaf(az, c.z, c.w + x1sq)));
        float key = __uint_as_float((__float_as_uint(dd) & 0xFFFFFF00u) | (unsigned)(s + u));
        int L = u & 1;
        insert_k(k[L][0], k[L][1], k[L][2], key);
      }
    }
    float e0 = k[0][0], e1 = k[0][1], e2 = k[0][2];
    insert_k(e0, e1, e2, k[1][0]);
    insert_k(e0, e1, e2, k[1][1]);
    insert_k(e0, e1, e2, k[1][2]);

    float ed[3]; int ei[3];
    float ev[3] = {e0, e1, e2};
    #pragma unroll
    for (int j = 0; j < 3; j++){
      int li = (int)(__float_as_uint(ev[j]) & 0xFFu);
      float4 c = pts[li];
      float dd = fmaf(ax, c.x, fmaf(ay, c.y, fmaf(az, c.z, c.w + x1sq)));
      ed[j] = fmaxf(dd, 0.f);
      ei[j] = base + li;
    }

    size_t g = (size_t)b * N_ + n;
    partd[(piece*3 + 0)*(size_t)M_ + g] = ed[0];
    partd[(piece*3 + 1)*(size_t)M_ + g] = ed[1];
    partd[(piece*3 + 2)*(size_t)M_ + g] = ed[2];
    parti[(piece*3 + 0)*(size_t)M_ + g] = ei[0];
    parti[(piece*3 + 1)*(size_t)M_ + g] = ei[1];
    parti[(piece*3 + 2)*(size_t)M_ + g] = ei[2];
    return;
  }

  const int pid = per*99 + (r - 16);           // [0,12672)
  if (pid < 384){
    int i = pid * 256 + t;
    if (i < 256*384){
      int row = i / 384, col = i - row*384;
      w1b[fragaddr(row, col, 384)] = f2bf(W1[i]);
    }
    if (i < 128*256){
      int row = i >> 8, col = i & 255;
      w2b[fragaddr(row, col, 256)] = f2bf(W2[i]);
    }
    if (i < 1536) stats[i] = 0.f;
    return;
  }
  int tx = t & 31, ty = t >> 5;
  if (pid < 4480){
    int id = pid - 384;
    int b = id >> 9, rem = id & 511;
    int l0 = (rem & 63) * 32, r0 = (rem >> 6) * 32;   // l: point in S, r: channel in C2
    const float* src = p2 + (size_t)b * C2_ * S_;
    #pragma unroll
    for (int rr = ty; rr < 32; rr += 8)
      tile[rr][tx] = src[(size_t)(r0 + rr) * S_ + l0 + tx];
    __syncthreads();
    unsigned short* dst = p2t + (size_t)b * S_ * C2_;
    #pragma unroll
    for (int rr = ty; rr < 32; rr += 8)
      dst[(size_t)(l0 + rr) * C2_ + r0 + tx] = f2bf(tile[tx][rr]);
    return;
  }
  {
    int id = pid - 4480;
    int b = id >> 10, rem = id & 1023;
    int l0 = (rem & 255) * 32, r0 = (rem >> 8) * 32;  // l: point in N, r: channel in C1
    const float* src = p1 + (size_t)b * C1_ * N_;
    #pragma unroll
    for (int rr = ty; rr < 32; rr += 8)
      tile[rr][tx] = src[(size_t)(r0 + rr) * N_ + l0 + tx];
    __syncthreads();
    #pragma unroll
    for (int rr = ty; rr < 32; rr += 8){
      int g = b * N_ + l0 + rr;
      size_t a = ((size_t)((g >> 4)*12 + (r0 >> 5)) << 9)
               + (size_t)((((tx >> 3) & 3) << 7) + ((g & 15) << 3) + (tx & 7));
      x[a] = f2bf(tile[tx][rr]);
    }
  }
}

// ---------------- merge: coalesced thread-per-query reduction of piece-partials ---------
// (R9-verified: replaced a ~30us latency chain with a ~5us BW-bound pass.)
__global__ __launch_bounds__(256) void merge_kernel(const float* __restrict__ partd,
                                                    const int* __restrict__ parti,
                                                    int* __restrict__ ibuf,
                                                    float* __restrict__ wbuf){
  size_t g = (size_t)blockIdx.x * 256 + threadIdx.x;
  float d0 = partd[0*(size_t)M_ + g], d1 = partd[1*(size_t)M_ + g], d2 = partd[2*(size_t)M_ + g];
  int   i0 = parti[0*(size_t)M_ + g], i1 = parti[1*(size_t)M_ + g], i2 = parti[2*(size_t)M_ + g];
  #pragma unroll
  for (int p = 1; p < PIECES_; p++)
    #pragma unroll
    for (int j = 0; j < 3; j++)
      insert3(d0, d1, d2, i0, i1, i2,
              partd[(p*3 + j)*(size_t)M_ + g], parti[(p*3 + j)*(size_t)M_ + g]);
  float r0 = 1.f/(d0 + 1e-8f), r1 = 1.f/(d1 + 1e-8f), r2 = 1.f/(d2 + 1e-8f);
  float rs = 1.f/(r0 + r1 + r2);
  ibuf[0*(size_t)M_ + g] = i0;    ibuf[1*(size_t)M_ + g] = i1;    ibuf[2*(size_t)M_ + g] = i2;
  wbuf[0*(size_t)M_ + g] = r0*rs; wbuf[1*(size_t)M_ + g] = r1*rs; wbuf[2*(size_t)M_ + g] = r2*rs;
}

// ---------------- gather: vectorized 4ch/lane interp into x cols 128..383 ---------------
// (R10-verified address math.) One wave per query, lane ln covers channels 4ln..4ln+3;
// p2t reads are ushort4 (512B/wave-request, p2t L2-resident), store is one 8B short4.
__global__ __launch_bounds__(256) void gather_kernel(
    const unsigned short* __restrict__ p2t, const int* __restrict__ ibuf,
    const float* __restrict__ wbuf, unsigned short* __restrict__ x)
{
  __shared__ int   sidx[48];
  __shared__ float swgt[48];
  const int t = threadIdx.x;
  int base = blockIdx.x * 16;
  if (t < 64){
    int q = t >> 2, j = t & 3;
    if (j < 3){
      sidx[q*3 + j] = ibuf[(size_t)j*M_ + base + q];
      swgt[q*3 + j] = wbuf[(size_t)j*M_ + base + q];
    }
  }
  __syncthreads();
  const int wv = t >> 6, ln = t & 63;
  #pragma unroll
  for (int kq = 0; kq < 4; kq++){
    int k = kq*4 + wv;                  // query slot 0..15, one per wave per step
    int g = base + k;
    int b = g >> 13;
    const unsigned short* p = p2t + (size_t)b * S_ * C2_;
    float a0 = 0.f, a1 = 0.f, a2 = 0.f, a3 = 0.f;
    #pragma unroll
    for (int j = 0; j < 3; j++){
      ushort4v v = *(const ushort4v*)(p + (size_t)sidx[k*3+j]*C2_ + 4*ln);
      float w = swgt[k*3+j];
      a0 = fmaf(w, bf2f(v[0]), a0);
      a1 = fmaf(w, bf2f(v[1]), a1);
      a2 = fmaf(w, bf2f(v[2]), a2);
      a3 = fmaf(w, bf2f(v[3]), a3);
    }
    short4v o;
    o[0] = (short)f2bf(a0); o[1] = (short)f2bf(a1);
    o[2] = (short)f2bf(a2); o[3] = (short)f2bf(a3);
    size_t a = ((size_t)((g >> 4)*12 + 4 + (ln >> 3)) << 9)
             + (size_t)((((ln >> 1) & 3) << 7) + ((g & 15) << 3) + ((ln & 1) * 4));
    *(short4v*)(x + a) = o;
  }
}

// ---------------- BN-affine + relu on one bf16x8 A-fragment ----------------
__device__ __forceinline__ bf16x8 bn_relu_frag(bf16x8 v, const float* a, const float* c, int kb){
  union { bf16x8 h; unsigned short s[8]; } u; u.h = v;
  union { float4 v4; float f[4]; } a0, a1, c0, c1;
  a0.v4 = *(const float4*)(a + kb);  a1.v4 = *(const float4*)(a + kb + 4);
  c0.v4 = *(const float4*)(c + kb);  c1.v4 = *(const float4*)(c + kb + 4);
  #pragma unroll
  for (int j = 0; j < 4; j++){
    float f0 = fmaf(a0.f[j], bf2f(u.s[j]),     c0.f[j]);
    float f1 = fmaf(a1.f[j], bf2f(u.s[j + 4]), c1.f[j]);
    u.s[j]     = f2bf(fmaxf(f0, 0.f));
    u.s[j + 4] = f2bf(fmaxf(f1, 0.f));
  }
  return u.h;
}

// ---------------- m97-style MFMA GEMM, BK=64, single-buffer (R1 structure) --------------
// Stats epilogue: NO global atomics (R3: ~2x on both GEMMs).
template<int K, bool HAS_AFF, bool OUT_FRAG>
__global__ __launch_bounds__(256) void gemm_lds_kernel(
    const unsigned short* __restrict__ A, const unsigned short* __restrict__ Wf,
    unsigned short* __restrict__ Cout, int Ntot,
    float* pbuf, const float* aff_a, const float* aff_c)
{
  constexpr int KT = K / 32;
  __shared__ unsigned short smA[128*64];   // 16 KB: [m-chunk 0..7][k-chunk 0..1][512]
  __shared__ unsigned short smB[128*64];   // 16 KB
  __shared__ float ldsStat[256];

  const int t = threadIdx.x;
  const int lane = t & 63, wave = t >> 6;
  const int ln = lane & 15, lq = lane >> 4;
  const int wm = wave >> 1, wn = wave & 1;
  const int mtb = blockIdx.x * 8;
  const int ntb = blockIdx.y * 8;
  const int mtw = mtb + wm * 4;
  const int n0  = blockIdx.y * 128 + wn * 64;

  ldsStat[t] = 0.f;

  const int c0 = 2*wave, c1 = 2*wave + 1;   // this wave's staging chunks

  const f32x4 fzero = {0.f, 0.f, 0.f, 0.f};
  f32x4 acc[4][4];
  #pragma unroll
  for (int i = 0; i < 4; i++)
    #pragma unroll
    for (int j = 0; j < 4; j++) acc[i][j] = fzero;

  for (int kk = 0; kk < KT; kk += 2){
    #pragma unroll
    for (int q = 0; q < 2; q++){
      gload_lds16(A  + (((size_t)((mtb + c0)*KT + kk + q)) << 9) + lane*8,
                  &smA[((c0*2 + q) << 9) + lane*8]);
      gload_lds16(A  + (((size_t)((mtb + c1)*KT + kk + q)) << 9) + lane*8,
                  &smA[((c1*2 + q) << 9) + lane*8]);
      gload_lds16(Wf + (((size_t)((ntb + c0)*KT + kk + q)) << 9) + lane*8,
                  &smB[((c0*2 + q) << 9) + lane*8]);
      gload_lds16(Wf + (((size_t)((ntb + c1)*KT + kk + q)) << 9) + lane*8,
                  &smB[((c1*2 + q) << 9) + lane*8]);
    }
    __syncthreads();
    #pragma unroll
    for (int q = 0; q < 2; q++){
      bf16x8 af[4], bfr[4];
      #pragma unroll
      for (int i = 0; i < 4; i++)
        af[i] = *(const bf16x8*)(&smA[(((wm*4 + i)*2 + q) << 9) + lane*8]);
      #pragma unroll
      for (int j = 0; j < 4; j++)
        bfr[j] = *(const bf16x8*)(&smB[(((wn*4 + j)*2 + q) << 9) + lane*8]);
      if (HAS_AFF){
        const int kb = (kk + q)*32 + lq*8;
        #pragma unroll
        for (int i = 0; i < 4; i++) af[i] = bn_relu_frag(af[i], aff_a, aff_c, kb);
      }
      #pragma unroll
      for (int i = 0; i < 4; i++)
        #pragma unroll
        for (int j = 0; j < 4; j++)
          acc[i][j] = __builtin_amdgcn_mfma_f32_16x16x32_bf16(af[i], bfr[j], acc[i][j], 0, 0, 0);
    }
    __syncthreads();
  }

  #pragma unroll
  for (int j = 0; j < 4; j++){
    int ncol = n0 + j*16 + ln;
    float s = 0.f, q = 0.f;
    #pragma unroll
    for (int i = 0; i < 4; i++){
      #pragma unroll
      for (int r = 0; r < 4; r++){
        float v = acc[i][j][r];
        if (OUT_FRAG){
          size_t a = ((size_t)((mtw + i)*8 + (ncol >> 5)) << 9)
                   + (size_t)((((ncol >> 3) & 3) << 7) + ((lq*4 + r) << 3) + (ncol & 7));
          Cout[a] = f2bf(v);
        } else {
          Cout[((size_t)((mtw + i)*16 + lq*4 + r)) * Ntot + ncol] = f2bf(v);
        }
        s += v; q += v*v;
      }
    }
    s += __shfl_xor(s, 16); s += __shfl_xor(s, 32);
    q += __shfl_xor(q, 16); q += __shfl_xor(q, 32);
    if (lq == 0){
      int colLocal = wn*64 + j*16 + ln;
      atomicAdd(&ldsStat[colLocal], s);          // LDS-scope only
      atomicAdd(&ldsStat[128 + colLocal], q);
    }
  }
  __syncthreads();
  // one coalesced 1KB burst per block; no device atomics anywhere
  pbuf[((size_t)(blockIdx.y * gridDim.x + blockIdx.x) << 8) + t] = ldsStat[t];
}

// ---------------- finalize BN: reduce per-block partials, a = g*rsqrt(var+eps) ----------
// pbuf layout: [grp(=by)][512 blocks][128 sum | 128 sq]; grid = C blocks, 256 threads.
__global__ __launch_bounds__(256) void finalize_kernel(const float* pbuf, const float* g,
                                                       const float* be, float* a_out,
                                                       float* c_out){
  __shared__ float red[8];
  int c = blockIdx.x, t = threadIdx.x;
  int grp = c >> 7, lc = c & 127;
  const float* base = pbuf + ((size_t)(grp * 512) << 8);
  float s = base[((size_t)t << 8) + lc]       + base[((size_t)(t + 256) << 8) + lc];
  float q = base[((size_t)t << 8) + 128 + lc] + base[((size_t)(t + 256) << 8) + 128 + lc];
  #pragma unroll
  for (int o = 1; o < 64; o <<= 1){ s += __shfl_xor(s, o); q += __shfl_xor(q, o); }
  int w = t >> 6;
  if ((t & 63) == 0){ red[w] = s; red[4 + w] = q; }
  __syncthreads();
  if (t == 0){
    s = red[0] + red[1] + red[2] + red[3];
    q = red[4] + red[5] + red[6] + red[7];
    float mean = s * (1.f / M_);
    float var  = q * (1.f / M_) - mean*mean;
    float a = g[c] * rsqrtf(var + 1e-5f);
    a_out[c] = a;
    c_out[c] = fmaf(-mean, a, be[c]);
  }
}

// ---------------- final: BN2-affine + relu + transpose to [B,128,N] fp32 ----------------
__global__ __launch_bounds__(256) void out_kernel(const unsigned short* y2, const float* a2,
                                                  const float* c2, float* out){
  __shared__ float lds[64][65];
  int t  = threadIdx.x;
  int b  = blockIdx.z;
  int n0 = blockIdx.y * 64;
  int c0 = blockIdx.x * 64;
  int cc = t & 63, tr = t >> 6;
  float a = a2[c0 + cc], cadd = c2[c0 + cc];
  #pragma unroll
  for (int ph = 0; ph < 16; ph++){
    int nr = tr + ph*4;
    unsigned short v = y2[((size_t)(b*N_ + n0 + nr)) * H2_ + c0 + cc];
    lds[nr][cc] = fmaxf(fmaf(a, bf2f(v), cadd), 0.f);
  }
  __syncthreads();
  #pragma unroll
  for (int ph = 0; ph < 16; ph++){
    int cr = tr + ph*4;
    out[((size_t)(b*H2_ + c0 + cr)) * N_ + n0 + cc] = lds[cc][cr];
  }
}

extern "C" void kernel_launch(void* const* d_in, const int* in_sizes, int n_in,
                              void* d_out, int out_size, void* d_ws, size_t ws_size,
                              hipStream_t stream){
  const float* xyz1 = (const float*)d_in[0];
  const float* xyz2 = (const float*)d_in[1];
  const float* p1   = (const float*)d_in[2];
  const float* p2   = (const float*)d_in[3];
  const float* W1   = (const float*)d_in[4];
  const float* g1   = (const float*)d_in[6];
  const float* be1  = (const float*)d_in[7];
  const float* W2   = (const float*)d_in[8];
  const float* g2   = (const float*)d_in[10];
  const float* be2  = (const float*)d_in[11];
  float* out = (float*)d_out;

  char* ws = (char*)d_ws;
  unsigned short* x    = (unsigned short*)(ws + 0);          // [65536][384] bf16 frag  50.3 MB
  unsigned short* p2t  = (unsigned short*)(ws + 50331648);   // [8][2048][256] bf16 row  8.4 MB
  unsigned short* y1   = (unsigned short*)(ws + 58720256);   // [65536][256] bf16 frag  33.6 MB
  unsigned short* y2   = (unsigned short*)(ws + 92274688);   // [65536][128] bf16 row   16.8 MB
  unsigned short* w1b  = (unsigned short*)(ws + 109051904);  // [256][384] bf16 frag
  unsigned short* w2b  = (unsigned short*)(ws + 109248512);  // [128][256] bf16 frag
  float*          stats= (float*)(ws + 110886912);           // a1/c1/a2/c2
  float* a1   = stats + 768;  float* c1  = stats + 1024;
  float* a2   = stats + 1280; float* c2  = stats + 1408;
  // knn partials in y1 region: partd [0,6.3MB), parti [12.6,18.9MB)
  float* partd = (float*)y1;
  int*   parti = (int*)(y1 + 6291456);
  // compact merged {idx,w} at y1+20MB / y1+22MB (dead before gemm1 overwrites y1)
  int*   ibuf = (int*)  (ws + 58720256 + 20971520);          // 768 KB
  float* wbuf = (float*)(ws + 58720256 + 23068672);          // 768 KB
  // gemm stats partials: gemm1 -> p2t region (dead after gather), gemm2 -> x region
  float* pbuf1 = (float*)p2t;
  float* pbuf2 = (float*)x;

  // fused front-end: 128 periods x (16 knn + 99 prep) = 14720 blocks (R5-verbatim)
  prep_knn_fused<<<14720, 256, 0, stream>>>(W1, W2, p2, p1, xyz1, xyz2,
                                            w1b, w2b, stats, p2t, x, partd, parti);
  // merge: coalesced thread-per-query partials reduction -> {idx3,w3}
  merge_kernel<<<256, 256, 0, stream>>>(partd, parti, ibuf, wbuf);
  // gather: vectorized interp into x cols 128..383
  gather_kernel<<<4096, 256, 0, stream>>>(p2t, ibuf, wbuf, x);
  // gemm1: M=65536, N=256, K=384; block 128x128 -> grid (512, 2); y1 in frag layout (K=256)
  gemm_lds_kernel<384, false, true><<<dim3(512, 2), 256, 0, stream>>>(
      x, w1b, y1, 256, pbuf1, nullptr, nullptr);
  finalize_kernel<<<256, 256, 0, stream>>>(pbuf1, g1, be1, a1, c1);
  // gemm2: M=65536, N=128, K=256; block 128x128 -> grid (512, 1); y2 row layout
  gemm_lds_kernel<256, true, false><<<dim3(512, 1), 256, 0, stream>>>(
      y1, w2b, y2, 128, pbuf2, a1, c1);
  finalize_kernel<<<128, 256, 0, stream>>>(pbuf2, g2, be2, a2, c2);
  out_kernel<<<dim3(2, 128, 8), 256, 0, stream>>>(y2, a2, c2, out);
}

// Round 12
// 234.260 us; speedup vs baseline: 1.1253x; 1.0371x over previous
//
#include <hip/hip_runtime.h>
#include <stdint.h>

#define B_ 8
#define N_ 8192
#define S_ 2048
#define C1_ 128
#define C2_ 256
#define IN_ 384
#define H1_ 256
#define H2_ 128
#define M_ (B_*N_)   // 65536 rows

typedef short bf16x8 __attribute__((ext_vector_type(8)));
typedef float f32x4 __attribute__((ext_vector_type(4)));
typedef short short4v __attribute__((ext_vector_type(4)));
typedef unsigned short ushort4v __attribute__((ext_vector_type(4)));

__device__ __forceinline__ float bf2f(unsigned short s){
  union { unsigned int u; float f; } x; x.u = ((unsigned int)s) << 16; return x.f;
}
__device__ __forceinline__ unsigned short f2bf(float f){
  union { float f; unsigned int u; } x; x.f = f;
  unsigned int u = x.u;
  unsigned int r = (u + 0x7FFFu + ((u >> 16) & 1u)) >> 16;
  return (unsigned short)r;
}

// fragment-major layout: element (m,k) of a row-major [M][K] matrix lives at
// tile (m/16, k/32) * 512 + lane-order offset; a wave's fragment = 1 KB contiguous burst.
__device__ __forceinline__ size_t fragaddr(int m, int k, int K){
  return ((size_t)((m >> 4) * (K >> 5) + (k >> 5)) << 9)
       + (size_t)((((k >> 3) & 3) << 7) + ((m & 15) << 3) + (k & 7));
}

// async global->LDS, 16B per lane (m97 mechanism: dest wave-uniform base + lane*16)
__device__ __forceinline__ void gload_lds16(const unsigned short* g, unsigned short* l){
  __builtin_amdgcn_global_load_lds(
      (const __attribute__((address_space(1))) unsigned int*)g,
      (__attribute__((address_space(3))) unsigned int*)l, 16, 0, 0);
}

#define PIECES_ 8
#define SPP_ (S_ / PIECES_)   // 256 -> local idx fits 8 bits

__device__ __forceinline__ void insert_k(float& k0, float& k1, float& k2, float x){
  k2 = __builtin_amdgcn_fmed3f(k1, k2, x);
  k1 = __builtin_amdgcn_fmed3f(k0, k1, x);
  k0 = fminf(k0, x);
}

__device__ __forceinline__ void insert3(float& d0, float& d1, float& d2,
                                        int& i0, int& i1, int& i2,
                                        float x, int s){
  bool b0 = x < d0, b1 = x < d1, b2 = x < d2;
  i2 = b1 ? i1 : (b2 ? s : i2);
  i1 = b0 ? i0 : (b1 ? s : i1);
  i0 = b0 ? s : i0;
  d2 = __builtin_amdgcn_fmed3f(d1, d2, x);
  d1 = __builtin_amdgcn_fmed3f(d0, d1, x);
  d0 = fminf(d0, x);
}

// ---------------- fused prep + knn: interleaved block roles (R5-verbatim, 242.3 best) ---
// 128 periods of 115 blocks: r<16 -> knn (2048 blocks, piece-split, VALU-bound);
// r>=16 -> prep (12672: weights/stats [0,384), p2t [384,4480), p1->x [4480,12672)).
// R10 lesson: every A/B re-split of these roles measured WORSE; do not re-split.
__global__ __launch_bounds__(256) void prep_knn_fused(
    const float* W1, const float* W2, const float* p2, const float* p1,
    const float* xyz1, const float* xyz2,
    unsigned short* w1b, unsigned short* w2b, float* stats,
    unsigned short* p2t, unsigned short* x,
    float* partd, int* parti)
{
  __shared__ __align__(16) char smraw[4224];               // union: tile 4224B | pts 4096B
  float (*tile)[33] = reinterpret_cast<float(*)[33]>(smraw);
  float4* pts = reinterpret_cast<float4*>(smraw);

  const int per = blockIdx.x / 115;
  const int r   = blockIdx.x % 115;
  const int t   = threadIdx.x;

  if (r < 16){
    // ---- knn role ----
    int kid = per*16 + r;                      // [0,2048)
    int nb = kid & 31, b = (kid >> 5) & 7, piece = kid >> 8;
    int n = nb*256 + t;
    int base = piece * SPP_;
    const float* x2 = xyz2 + (size_t)b * 3 * S_;
    {
      float px = x2[base + t], py = x2[S_ + base + t], pz = x2[2*S_ + base + t];
      pts[t] = make_float4(-2.f*px, -2.f*py, -2.f*pz, px*px + py*py + pz*pz);
    }
    __syncthreads();
    const float* x1 = xyz1 + (size_t)b * 3 * N_;
    float ax = x1[n], ay = x1[N_ + n], az = x1[2*N_ + n];
    float x1sq = ax*ax + ay*ay + az*az;

    const float KINIT = __uint_as_float(0x7F000000u);
    float k[2][3];
    k[0][0]=k[0][1]=k[0][2]=KINIT;
    k[1][0]=k[1][1]=k[1][2]=KINIT;

    for (int s = 0; s < SPP_; s += 8){
      #pragma unroll
      for (int u = 0; u < 8; u++){
        float4 c = pts[s + u];
        float dd = fmaf(ax, c.x, fmaf(ay, c.y, fmaf(az, c.z, c.w + x1sq)));
        float key = __uint_as_float((__float_as_uint(dd) & 0xFFFFFF00u) | (unsigned)(s + u));
        int L = u & 1;
        insert_k(k[L][0], k[L][1], k[L][2], key);
      }
    }
    float e0 = k[0][0], e1 = k[0][1], e2 = k[0][2];
    insert_k(e0, e1, e2, k[1][0]);
    insert_k(e0, e1, e2, k[1][1]);
    insert_k(e0, e1, e2, k[1][2]);

    float ed[3]; int ei[3];
    float ev[3] = {e0, e1, e2};
    #pragma unroll
    for (int j = 0; j < 3; j++){
      int li = (int)(__float_as_uint(ev[j]) & 0xFFu);
      float4 c = pts[li];
      float dd = fmaf(ax, c.x, fmaf(ay, c.y, fmaf(az, c.z, c.w + x1sq)));
      ed[j] = fmaxf(dd, 0.f);
      ei[j] = base + li;
    }

    size_t g = (size_t)b * N_ + n;
    partd[(piece*3 + 0)*(size_t)M_ + g] = ed[0];
    partd[(piece*3 + 1)*(size_t)M_ + g] = ed[1];
    partd[(piece*3 + 2)*(size_t)M_ + g] = ed[2];
    parti[(piece*3 + 0)*(size_t)M_ + g] = ei[0];
    parti[(piece*3 + 1)*(size_t)M_ + g] = ei[1];
    parti[(piece*3 + 2)*(size_t)M_ + g] = ei[2];
    return;
  }

  const int pid = per*99 + (r - 16);           // [0,12672)
  if (pid < 384){
    int i = pid * 256 + t;
    if (i < 256*384){
      int row = i / 384, col = i - row*384;
      w1b[fragaddr(row, col, 384)] = f2bf(W1[i]);
    }
    if (i < 128*256){
      int row = i >> 8, col = i & 255;
      w2b[fragaddr(row, col, 256)] = f2bf(W2[i]);
    }
    if (i < 1536) stats[i] = 0.f;
    return;
  }
  int tx = t & 31, ty = t >> 5;
  if (pid < 4480){
    int id = pid - 384;
    int b = id >> 9, rem = id & 511;
    int l0 = (rem & 63) * 32, r0 = (rem >> 6) * 32;   // l: point in S, r: channel in C2
    const float* src = p2 + (size_t)b * C2_ * S_;
    #pragma unroll
    for (int rr = ty; rr < 32; rr += 8)
      tile[rr][tx] = src[(size_t)(r0 + rr) * S_ + l0 + tx];
    __syncthreads();
    unsigned short* dst = p2t + (size_t)b * S_ * C2_;
    #pragma unroll
    for (int rr = ty; rr < 32; rr += 8)
      dst[(size_t)(l0 + rr) * C2_ + r0 + tx] = f2bf(tile[tx][rr]);
    return;
  }
  {
    int id = pid - 4480;
    int b = id >> 10, rem = id & 1023;
    int l0 = (rem & 255) * 32, r0 = (rem >> 8) * 32;  // l: point in N, r: channel in C1
    const float* src = p1 + (size_t)b * C1_ * N_;
    #pragma unroll
    for (int rr = ty; rr < 32; rr += 8)
      tile[rr][tx] = src[(size_t)(r0 + rr) * N_ + l0 + tx];
    __syncthreads();
    #pragma unroll
    for (int rr = ty; rr < 32; rr += 8){
      int g = b * N_ + l0 + rr;
      size_t a = ((size_t)((g >> 4)*12 + (r0 >> 5)) << 9)
               + (size_t)((((tx >> 3) & 3) << 7) + ((g & 15) << 3) + (tx & 7));
      x[a] = f2bf(tile[tx][rr]);
    }
  }
}

// ---------------- merge: coalesced thread-per-query reduction of piece-partials ---------
// (R9-verified: replaced a ~30us latency chain with a ~5us BW-bound pass.)
__global__ __launch_bounds__(256) void merge_kernel(const float* __restrict__ partd,
                                                    const int* __restrict__ parti,
                                                    int* __restrict__ ibuf,
                                                    float* __restrict__ wbuf){
  size_t g = (size_t)blockIdx.x * 256 + threadIdx.x;
  float d0 = partd[0*(size_t)M_ + g], d1 = partd[1*(size_t)M_ + g], d2 = partd[2*(size_t)M_ + g];
  int   i0 = parti[0*(size_t)M_ + g], i1 = parti[1*(size_t)M_ + g], i2 = parti[2*(size_t)M_ + g];
  #pragma unroll
  for (int p = 1; p < PIECES_; p++)
    #pragma unroll
    for (int j = 0; j < 3; j++)
      insert3(d0, d1, d2, i0, i1, i2,
              partd[(p*3 + j)*(size_t)M_ + g], parti[(p*3 + j)*(size_t)M_ + g]);
  float r0 = 1.f/(d0 + 1e-8f), r1 = 1.f/(d1 + 1e-8f), r2 = 1.f/(d2 + 1e-8f);
  float rs = 1.f/(r0 + r1 + r2);
  ibuf[0*(size_t)M_ + g] = i0;    ibuf[1*(size_t)M_ + g] = i1;    ibuf[2*(size_t)M_ + g] = i2;
  wbuf[0*(size_t)M_ + g] = r0*rs; wbuf[1*(size_t)M_ + g] = r1*rs; wbuf[2*(size_t)M_ + g] = r2*rs;
}

// ---------------- gather: vectorized 4ch/lane interp into x cols 128..383 ---------------
// (R10/R11-verified.) One wave per query, lane ln covers channels 4ln..4ln+3.
__global__ __launch_bounds__(256) void gather_kernel(
    const unsigned short* __restrict__ p2t, const int* __restrict__ ibuf,
    const float* __restrict__ wbuf, unsigned short* __restrict__ x)
{
  __shared__ int   sidx[48];
  __shared__ float swgt[48];
  const int t = threadIdx.x;
  int base = blockIdx.x * 16;
  if (t < 64){
    int q = t >> 2, j = t & 3;
    if (j < 3){
      sidx[q*3 + j] = ibuf[(size_t)j*M_ + base + q];
      swgt[q*3 + j] = wbuf[(size_t)j*M_ + base + q];
    }
  }
  __syncthreads();
  const int wv = t >> 6, ln = t & 63;
  #pragma unroll
  for (int kq = 0; kq < 4; kq++){
    int k = kq*4 + wv;                  // query slot 0..15, one per wave per step
    int g = base + k;
    int b = g >> 13;
    const unsigned short* p = p2t + (size_t)b * S_ * C2_;
    float a0 = 0.f, a1 = 0.f, a2 = 0.f, a3 = 0.f;
    #pragma unroll
    for (int j = 0; j < 3; j++){
      ushort4v v = *(const ushort4v*)(p + (size_t)sidx[k*3+j]*C2_ + 4*ln);
      float w = swgt[k*3+j];
      a0 = fmaf(w, bf2f(v[0]), a0);
      a1 = fmaf(w, bf2f(v[1]), a1);
      a2 = fmaf(w, bf2f(v[2]), a2);
      a3 = fmaf(w, bf2f(v[3]), a3);
    }
    short4v o;
    o[0] = (short)f2bf(a0); o[1] = (short)f2bf(a1);
    o[2] = (short)f2bf(a2); o[3] = (short)f2bf(a3);
    size_t a = ((size_t)((g >> 4)*12 + 4 + (ln >> 3)) << 9)
             + (size_t)((((ln >> 1) & 3) << 7) + ((g & 15) << 3) + ((ln & 1) * 4));
    *(short4v*)(x + a) = o;
  }
}

// ---------------- BN-affine + relu on one bf16x8 A-fragment ----------------
__device__ __forceinline__ bf16x8 bn_relu_frag(bf16x8 v, const float* a, const float* c, int kb){
  union { bf16x8 h; unsigned short s[8]; } u; u.h = v;
  union { float4 v4; float f[4]; } a0, a1, c0, c1;
  a0.v4 = *(const float4*)(a + kb);  a1.v4 = *(const float4*)(a + kb + 4);
  c0.v4 = *(const float4*)(c + kb);  c1.v4 = *(const float4*)(c + kb + 4);
  #pragma unroll
  for (int j = 0; j < 4; j++){
    float f0 = fmaf(a0.f[j], bf2f(u.s[j]),     c0.f[j]);
    float f1 = fmaf(a1.f[j], bf2f(u.s[j + 4]), c1.f[j]);
    u.s[j]     = f2bf(fmaxf(f0, 0.f));
    u.s[j + 4] = f2bf(fmaxf(f1, 0.f));
  }
  return u.h;
}

// ---------------- MFMA GEMM: BK=32 double-buffer, T3-minimum 2-phase ------------------
// R11 ledger: gemms ~2.5x off roofline -- the single-buffer loop serializes {stage-drain,
// compute} each iter. Fix: issue next k-chunk's global_load_lds BEFORE computing current
// (loads fly under MFMA; one vmcnt(0)+barrier per iter). R1's dbuf failure causes are
// addressed: BK=32 keeps LDS at 32KB total (2x 8KB x A,B) -> same 4 blocks/CU as the
// single-buffer version, same L2 co-residency. One k-chunk = exactly one wave-gload (1KB).
template<int K, bool HAS_AFF, bool OUT_FRAG>
__global__ __launch_bounds__(256) void gemm_lds_kernel(
    const unsigned short* __restrict__ A, const unsigned short* __restrict__ Wf,
    unsigned short* __restrict__ Cout, int Ntot,
    float* pbuf, const float* aff_a, const float* aff_c)
{
  constexpr int KT = K / 32;               // 12 or 8 k-chunks
  __shared__ unsigned short smA[2][128*32];   // 2 x 8 KB: [8 m-chunks][512]
  __shared__ unsigned short smB[2][128*32];   // 2 x 8 KB
  __shared__ float ldsStat[256];

  const int t = threadIdx.x;
  const int lane = t & 63, wave = t >> 6;
  const int ln = lane & 15, lq = lane >> 4;
  const int wm = wave >> 1, wn = wave & 1;
  const int mtb = blockIdx.x * 8;
  const int ntb = blockIdx.y * 8;
  const int mtw = mtb + wm * 4;
  const int n0  = blockIdx.y * 128 + wn * 64;

  ldsStat[t] = 0.f;

  const int c0 = 2*wave, c1 = 2*wave + 1;   // this wave's staging chunks

  auto stage = [&](int buf, int kc){
    gload_lds16(A  + (((size_t)((mtb + c0)*KT + kc)) << 9) + lane*8,
                &smA[buf][(c0 << 9) + lane*8]);
    gload_lds16(A  + (((size_t)((mtb + c1)*KT + kc)) << 9) + lane*8,
                &smA[buf][(c1 << 9) + lane*8]);
    gload_lds16(Wf + (((size_t)((ntb + c0)*KT + kc)) << 9) + lane*8,
                &smB[buf][(c0 << 9) + lane*8]);
    gload_lds16(Wf + (((size_t)((ntb + c1)*KT + kc)) << 9) + lane*8,
                &smB[buf][(c1 << 9) + lane*8]);
  };

  const f32x4 fzero = {0.f, 0.f, 0.f, 0.f};
  f32x4 acc[4][4];
  #pragma unroll
  for (int i = 0; i < 4; i++)
    #pragma unroll
    for (int j = 0; j < 4; j++) acc[i][j] = fzero;

  stage(0, 0);
  __syncthreads();                          // prologue drain of chunk 0

  #pragma unroll
  for (int it = 0; it < KT; ++it){
    const int cur = it & 1;                 // compile-time after full unroll
    if (it + 1 < KT) stage(cur ^ 1, it + 1);  // prefetch flies under this iter's MFMA
    bf16x8 af[4], bfr[4];
    #pragma unroll
    for (int i = 0; i < 4; i++)
      af[i] = *(const bf16x8*)(&smA[cur][((wm*4 + i) << 9) + lane*8]);
    #pragma unroll
    for (int j = 0; j < 4; j++)
      bfr[j] = *(const bf16x8*)(&smB[cur][((wn*4 + j) << 9) + lane*8]);
    if (HAS_AFF){
      const int kb = it*32 + lq*8;
      #pragma unroll
      for (int i = 0; i < 4; i++) af[i] = bn_relu_frag(af[i], aff_a, aff_c, kb);
    }
    #pragma unroll
    for (int i = 0; i < 4; i++)
      #pragma unroll
      for (int j = 0; j < 4; j++)
        acc[i][j] = __builtin_amdgcn_mfma_f32_16x16x32_bf16(af[i], bfr[j], acc[i][j], 0, 0, 0);
    __syncthreads();                        // vmcnt drain: prefetch had MFMA-time in flight
  }

  #pragma unroll
  for (int j = 0; j < 4; j++){
    int ncol = n0 + j*16 + ln;
    float s = 0.f, q = 0.f;
    #pragma unroll
    for (int i = 0; i < 4; i++){
      #pragma unroll
      for (int r = 0; r < 4; r++){
        float v = acc[i][j][r];
        if (OUT_FRAG){
          size_t a = ((size_t)((mtw + i)*8 + (ncol >> 5)) << 9)
                   + (size_t)((((ncol >> 3) & 3) << 7) + ((lq*4 + r) << 3) + (ncol & 7));
          Cout[a] = f2bf(v);
        } else {
          Cout[((size_t)((mtw + i)*16 + lq*4 + r)) * Ntot + ncol] = f2bf(v);
        }
        s += v; q += v*v;
      }
    }
    s += __shfl_xor(s, 16); s += __shfl_xor(s, 32);
    q += __shfl_xor(q, 16); q += __shfl_xor(q, 32);
    if (lq == 0){
      int colLocal = wn*64 + j*16 + ln;
      atomicAdd(&ldsStat[colLocal], s);          // LDS-scope only
      atomicAdd(&ldsStat[128 + colLocal], q);
    }
  }
  __syncthreads();
  // one coalesced 1KB burst per block; no device atomics anywhere
  pbuf[((size_t)(blockIdx.y * gridDim.x + blockIdx.x) << 8) + t] = ldsStat[t];
}

// ---------------- finalize BN: reduce per-block partials, a = g*rsqrt(var+eps) ----------
// pbuf layout: [grp(=by)][512 blocks][128 sum | 128 sq]; grid = C blocks, 256 threads.
__global__ __launch_bounds__(256) void finalize_kernel(const float* pbuf, const float* g,
                                                       const float* be, float* a_out,
                                                       float* c_out){
  __shared__ float red[8];
  int c = blockIdx.x, t = threadIdx.x;
  int grp = c >> 7, lc = c & 127;
  const float* base = pbuf + ((size_t)(grp * 512) << 8);
  float s = base[((size_t)t << 8) + lc]       + base[((size_t)(t + 256) << 8) + lc];
  float q = base[((size_t)t << 8) + 128 + lc] + base[((size_t)(t + 256) << 8) + 128 + lc];
  #pragma unroll
  for (int o = 1; o < 64; o <<= 1){ s += __shfl_xor(s, o); q += __shfl_xor(q, o); }
  int w = t >> 6;
  if ((t & 63) == 0){ red[w] = s; red[4 + w] = q; }
  __syncthreads();
  if (t == 0){
    s = red[0] + red[1] + red[2] + red[3];
    q = red[4] + red[5] + red[6] + red[7];
    float mean = s * (1.f / M_);
    float var  = q * (1.f / M_) - mean*mean;
    float a = g[c] * rsqrtf(var + 1e-5f);
    a_out[c] = a;
    c_out[c] = fmaf(-mean, a, be[c]);
  }
}

// ---------------- final: BN2-affine + relu + transpose to [B,128,N] fp32 ----------------
__global__ __launch_bounds__(256) void out_kernel(const unsigned short* y2, const float* a2,
                                                  const float* c2, float* out){
  __shared__ float lds[64][65];
  int t  = threadIdx.x;
  int b  = blockIdx.z;
  int n0 = blockIdx.y * 64;
  int c0 = blockIdx.x * 64;
  int cc = t & 63, tr = t >> 6;
  float a = a2[c0 + cc], cadd = c2[c0 + cc];
  #pragma unroll
  for (int ph = 0; ph < 16; ph++){
    int nr = tr + ph*4;
    unsigned short v = y2[((size_t)(b*N_ + n0 + nr)) * H2_ + c0 + cc];
    lds[nr][cc] = fmaxf(fmaf(a, bf2f(v), cadd), 0.f);
  }
  __syncthreads();
  #pragma unroll
  for (int ph = 0; ph < 16; ph++){
    int cr = tr + ph*4;
    out[((size_t)(b*H2_ + c0 + cr)) * N_ + n0 + cc] = lds[cc][cr];
  }
}

extern "C" void kernel_launch(void* const* d_in, const int* in_sizes, int n_in,
                              void* d_out, int out_size, void* d_ws, size_t ws_size,
                              hipStream_t stream){
  const float* xyz1 = (const float*)d_in[0];
  const float* xyz2 = (const float*)d_in[1];
  const float* p1   = (const float*)d_in[2];
  const float* p2   = (const float*)d_in[3];
  const float* W1   = (const float*)d_in[4];
  const float* g1   = (const float*)d_in[6];
  const float* be1  = (const float*)d_in[7];
  const float* W2   = (const float*)d_in[8];
  const float* g2   = (const float*)d_in[10];
  const float* be2  = (const float*)d_in[11];
  float* out = (float*)d_out;

  char* ws = (char*)d_ws;
  unsigned short* x    = (unsigned short*)(ws + 0);          // [65536][384] bf16 frag  50.3 MB
  unsigned short* p2t  = (unsigned short*)(ws + 50331648);   // [8][2048][256] bf16 row  8.4 MB
  unsigned short* y1   = (unsigned short*)(ws + 58720256);   // [65536][256] bf16 frag  33.6 MB
  unsigned short* y2   = (unsigned short*)(ws + 92274688);   // [65536][128] bf16 row   16.8 MB
  unsigned short* w1b  = (unsigned short*)(ws + 109051904);  // [256][384] bf16 frag
  unsigned short* w2b  = (unsigned short*)(ws + 109248512);  // [128][256] bf16 frag
  float*          stats= (float*)(ws + 110886912);           // a1/c1/a2/c2
  float* a1   = stats + 768;  float* c1  = stats + 1024;
  float* a2   = stats + 1280; float* c2  = stats + 1408;
  // knn partials in y1 region: partd [0,6.3MB), parti [12.6,18.9MB)
  float* partd = (float*)y1;
  int*   parti = (int*)(y1 + 6291456);
  // compact merged {idx,w} at y1+20MB / y1+22MB (dead before gemm1 overwrites y1)
  int*   ibuf = (int*)  (ws + 58720256 + 20971520);          // 768 KB
  float* wbuf = (float*)(ws + 58720256 + 23068672);          // 768 KB
  // gemm stats partials: gemm1 -> p2t region (dead after gather), gemm2 -> x region
  float* pbuf1 = (float*)p2t;
  float* pbuf2 = (float*)x;

  // fused front-end: 128 periods x (16 knn + 99 prep) = 14720 blocks (R5-verbatim)
  prep_knn_fused<<<14720, 256, 0, stream>>>(W1, W2, p2, p1, xyz1, xyz2,
                                            w1b, w2b, stats, p2t, x, partd, parti);
  // merge: coalesced thread-per-query partials reduction -> {idx3,w3}
  merge_kernel<<<256, 256, 0, stream>>>(partd, parti, ibuf, wbuf);
  // gather: vectorized interp into x cols 128..383
  gather_kernel<<<4096, 256, 0, stream>>>(p2t, ibuf, wbuf, x);
  // gemm1: M=65536, N=256, K=384; block 128x128 -> grid (512, 2); y1 in frag layout (K=256)
  gemm_lds_kernel<384, false, true><<<dim3(512, 2), 256, 0, stream>>>(
      x, w1b, y1, 256, pbuf1, nullptr, nullptr);
  finalize_kernel<<<256, 256, 0, stream>>>(pbuf1, g1, be1, a1, c1);
  // gemm2: M=65536, N=128, K=256; block 128x128 -> grid (512, 1); y2 row layout
  gemm_lds_kernel<256, true, false><<<dim3(512, 1), 256, 0, stream>>>(
      y1, w2b, y2, 128, pbuf2, a1, c1);
  finalize_kernel<<<128, 256, 0, stream>>>(pbuf2, g2, be2, a2, c2);
  out_kernel<<<dim3(2, 128, 8), 256, 0, stream>>>(y2, a2, c2, out);
}